// Round 4
// baseline (154.353 us; speedup 1.0000x reference)
//
#include <hip/hip_runtime.h>
#include <hip/hip_fp16.h>

#define Bn   4
#define CINc 64
#define COUTc 64
#define Hn   128
#define Wn   128
#define HW   (Hn * Wn)
#define KKc  9
#define NOFF 18

typedef short bf16x8 __attribute__((ext_vector_type(8)));
typedef float f32x4  __attribute__((ext_vector_type(4)));
typedef float f32x2  __attribute__((ext_vector_type(2)));

__device__ inline unsigned short f2bf(float f) {   // RNE fp32 -> bf16
    unsigned int u = __float_as_uint(f);
    return (unsigned short)((u + 0x7fffu + ((u >> 16) & 1u)) >> 16);
}

// 16B global -> LDS DMA. lds base wave-uniform; HW writes lane's 16B at
// ldsbase + lane*16.
__device__ inline void dma16(const void* g, void* l) {
#if __has_builtin(__builtin_amdgcn_global_load_lds)
    __builtin_amdgcn_global_load_lds(
        (__attribute__((address_space(1))) void*)(g),
        (__attribute__((address_space(3))) void*)(l), 16, 0, 0);
#else
    *(uint4*)l = *(const uint4*)g;
#endif
}

// ---------------------------------------------------------------------------
// prep_all: blocks 0..1023 transpose x -> channel-last bf16 xt;
// blocks 1024..1239 build lane-order swizzled weight tables.
// v12: wkb is grouped by cout-half: [ch][36 segs], seg=(k*2+kc)*2+ot2.
// ---------------------------------------------------------------------------
__global__ __launch_bounds__(256) void prep_all(
        const float* __restrict__ x, unsigned short* __restrict__ xt,
        const float* __restrict__ w_off, const float* __restrict__ w_def,
        unsigned short* __restrict__ wkb_sw, unsigned short* __restrict__ wob_sw) {
    int gb = blockIdx.x;
    int t  = threadIdx.x;
    if (gb < 1024) {
        __shared__ float s[64][65];
        int half = gb & 1;
        int h    = (gb >> 1) & 127;
        int b    = gb >> 8;
        int w0   = half * 64;
        int w = t & 63, cg = t >> 6;

        const float* xb = x + (size_t)b * CINc * HW + (size_t)h * Wn + w0 + w;
        #pragma unroll
        for (int i = 0; i < 16; ++i) {
            int c = cg * 16 + i;
            s[c][w] = xb[(size_t)c * HW];
        }
        __syncthreads();

        int cpair = t & 31, pxg = t >> 5;
        unsigned* xtp = (unsigned*)xt;
        #pragma unroll
        for (int i = 0; i < 8; ++i) {
            int px = pxg * 8 + i;
            float v0 = s[cpair * 2][px], v1 = s[cpair * 2 + 1][px];
            unsigned d = (unsigned)f2bf(v0) | ((unsigned)f2bf(v1) << 16);
            xtp[(((size_t)(b * Hn + h) * Wn) + w0 + px) * 32 + cpair] = d;
        }
        return;
    }
    int idx = (gb - 1024) * 256 + t;
    if (idx < 36864) {
        int j = idx & 7, l = (idx >> 3) & 63, s = idx >> 9;
        int k = s >> 3, kc = (s >> 2) & 1, ot = s & 3;
        int l15 = l & 15, quad = l >> 4;
        int o = ot * 16 + l15, c = kc * 32 + quad * 8 + j;
        int chh = ot >> 1, ot2 = ot & 1;                 // cout half, sub-tile
        int dst = chh * 18432 + ((((k * 2 + kc) * 2) + ot2) << 9) + l * 8 + j;
        wkb_sw[dst] = f2bf(w_def[((size_t)o * 64 + c) * 9 + k]);
    }
    int i2 = idx - 36864;
    if (i2 >= 0 && i2 < 18432) {
        int j = i2 & 7, l = (i2 >> 3) & 63, s = i2 >> 9;
        int tt = s >> 2, kc = (s >> 1) & 1, mt = s & 1;
        int l15 = l & 15, quad = l >> 4;
        int m = mt * 16 + l15, c = kc * 32 + quad * 8 + j;
        unsigned short v = 0;
        if (m < NOFF) v = f2bf(w_off[((size_t)m * 64 + c) * 9 + tt]);
        wob_sw[i2] = v;
    }
}

// ---------------------------------------------------------------------------
// Fused deformable conv v12. Block = (b, h, cout-half): 1024 blocks, 512 thr
// (8 waves x 16 px = full 128-px row; each block computes 32 of 64 couts).
// LDS = 36.9 KB (wob table == wkb-half table, time-shared) -> 3 blocks/CU
// with launch_bounds(512,6) (reg cap 85) vs v11's 2 blocks @ 73.7 KB.
// Offset conv + gather + interp duplicated per half (pipes were 81% idle).
// Register diet for the 85-cap: depth-4 rolling offset prefetch (32 regs,
// was 72), packed ad[9] tap addresses (9 regs, was 18+18), acc[2] (was 4).
// ---------------------------------------------------------------------------
__global__ __launch_bounds__(512, 6) void fused_deform_v12(
        const unsigned short* __restrict__ xt,
        const unsigned short* __restrict__ wob_sw,
        const unsigned short* __restrict__ wkb_sw,
        const float* __restrict__ b_off, float* __restrict__ out) {
    __shared__ bf16x8 s_w[36 * 64];         // 36864 B (wob 36 segs == wkb-half)

    int gid  = blockIdx.x;                  // 1024
    int ch   = gid >> 9;                    // cout half (0: 0..31, 1: 32..63)
    int g    = gid & 511;
    int xcd  = g & 7;                       // pairs (g, g+512) share XCD -> L2
    int j    = g >> 3;                      // 0..63
    int hh   = j & 15;
    int b    = j >> 4;
    int h    = xcd * 16 + hh;
    int tid  = threadIdx.x;
    int lane = tid & 63;
    int wave = __builtin_amdgcn_readfirstlane(tid >> 6);   // 0..7
    int l15  = lane & 15;
    int quad = lane >> 4;
    int p    = wave * 16 + l15;             // this lane's pixel col (0..127)

    // ---- stage wob -> s_w[0..36 segs) via DMA ----
    #pragma unroll
    for (int i = 0; i < 5; ++i) {
        int seg = i * 8 + wave;             // wave-uniform
        if (seg < 36) {
            int ebase = seg * 64;
            dma16((const uint4*)wob_sw + ebase + lane,
                  (char*)s_w + (size_t)ebase * 16);
        }
    }

    // ---- bias prefetch (hides under DMA drain) ----
    float4 bo  = ((const float4*)b_off)[quad];
    float2 bo8 = ((const float2*)b_off)[8];

    // ---- depth-4 rolling prefetch of the 9 offset-tap fragments ----
    const unsigned short* xtb = xt + (size_t)b * HW * 64;
    uint4 L[4][2];
    unsigned msk4[4];
    #define ISSUE(t9)                                                   \
        do {                                                            \
            int ty = (t9) / 3, tx = (t9) % 3;                           \
            int y  = h - 1 + ty;                                        \
            int xg = p - 1 + tx;                                        \
            bool v = (y >= 0) && (y < Hn) && (xg >= 0) && (xg < Wn);    \
            msk4[(t9) & 3] = v ? 0xFFFFFFFFu : 0u;                      \
            int yc = min(max(y, 0), Hn - 1);                            \
            int xc = min(max(xg, 0), Wn - 1);                           \
            size_t base = ((size_t)yc * Wn + xc) * 64;                  \
            L[(t9) & 3][0] = *(const uint4*)(xtb + base + quad * 8);    \
            L[(t9) & 3][1] = *(const uint4*)(xtb + base + 32 + quad * 8); \
        } while (0)
    ISSUE(0); ISSUE(1); ISSUE(2); ISSUE(3);
    __syncthreads();                        // bar0: wob DMA drained

    // ---- offset conv phase: 36 MFMA, rolling loads ----
    f32x4 oa0 = (f32x4){0.f, 0.f, 0.f, 0.f};
    f32x4 oa1 = (f32x4){0.f, 0.f, 0.f, 0.f};
    #pragma unroll
    for (int t9 = 0; t9 < 9; ++t9) {
        unsigned m = msk4[t9 & 3];
        #pragma unroll
        for (int kc = 0; kc < 2; ++kc) {
            union { bf16x8 v; uint4 u; } bf;
            bf.u = L[t9 & 3][kc];
            bf.u.x &= m; bf.u.y &= m; bf.u.z &= m; bf.u.w &= m;
            bf16x8 a0 = s_w[((t9 * 2 + kc) * 2 + 0) * 64 + lane];
            bf16x8 a1 = s_w[((t9 * 2 + kc) * 2 + 1) * 64 + lane];
            oa0 = __builtin_amdgcn_mfma_f32_16x16x32_bf16(a0, bf.v, oa0, 0, 0, 0);
            oa1 = __builtin_amdgcn_mfma_f32_16x16x32_bf16(a1, bf.v, oa1, 0, 0, 0);
        }
        if (t9 < 5) {
            switch (t9) {                   // compile-time ISSUE(t9+4)
                case 0: ISSUE(4); break;
                case 1: ISSUE(5); break;
                case 2: ISSUE(6); break;
                case 3: ISSUE(7); break;
                case 4: ISSUE(8); break;
            }
        }
    }
    #undef ISSUE

    // ---- phase-1 in registers; lane (l15,q) computes taps 2q,2q+1 (+8:q0)
    unsigned my_ad[3]  = {0, 0, 0};
    unsigned my_w01[3] = {0, 0, 0};
    unsigned my_w23[3] = {0, 0, 0};
    auto phase1 = [&](int k, float dy, float dx, int slot) {
        float py  = (float)(h - 1 + k / 3) + dy;
        float pxf = (float)(p - 1 + k % 3) + dx;
        float y0f = floorf(py), x0f = floorf(pxf);
        float fy = py - y0f, fx = pxf - x0f;
        int y0 = (int)y0f, x0 = (int)x0f;
        bool vy0 = (y0 >= 0) & (y0 < Hn);
        bool vy1 = (y0 + 1 >= 0) & (y0 + 1 < Hn);
        bool vx0 = (x0 >= 0) & (x0 < Wn);
        bool vx1 = (x0 + 1 >= 0) & (x0 + 1 < Wn);
        float wy0 = vy0 ? 1.f - fy : 0.f;
        float wy1 = vy1 ? fy : 0.f;
        float wx0 = vx0 ? 1.f - fx : 0.f;
        float wx1 = vx1 ? fx : 0.f;
        int xc = min(max(x0, 0), Wn - 2);               // pair base
        bool sel0 = (min(max(x0, 0), Wn - 1) != xc);
        bool sel1 = ((min(max(x0 + 1, 0), Wn - 1) - xc) == 1);
        float Wa = (sel0 ? 0.f : wx0) + (sel1 ? 0.f : wx1);
        float Wb = (sel0 ? wx0 : 0.f) + (sel1 ? wx1 : 0.f);
        int yc0 = min(max(y0, 0), Hn - 1), yc1 = min(max(y0 + 1, 0), Hn - 1);
        union { __half2 hv; unsigned u; } c01, c23;
        c01.hv = __floats2half2_rn(wy0 * Wa, wy0 * Wb);
        c23.hv = __floats2half2_rn(wy1 * Wa, wy1 * Wb);
        my_ad[slot]  = (unsigned)yc0 | ((unsigned)yc1 << 8) | ((unsigned)xc << 16);
        my_w01[slot] = c01.u;
        my_w23[slot] = c23.u;
    };
    int kb = quad * 2;
    phase1(kb,     oa0[0] + bo.x, oa0[1] + bo.y, 0);
    phase1(kb + 1, oa0[2] + bo.z, oa0[3] + bo.w, 1);
    if (quad == 0)
        phase1(8, oa1[0] + bo8.x, oa1[1] + bo8.y, 2);
    __syncthreads();                        // bar1: all wob ds_reads done

    // ---- overwrite s_w with this half's wkb via DMA (shuffles cover) ----
    const unsigned short* wkh = wkb_sw + (size_t)ch * 18432;
    #pragma unroll
    for (int i = 0; i < 5; ++i) {
        int seg = i * 8 + wave;             // 36 segs over 8 waves
        if (seg < 36) {
            int ebase = seg * 64;
            dma16((const uint4*)wkh + ebase + lane,
                  (char*)s_w + (size_t)ebase * 16);
        }
    }

    // ---- redistribute phase-1 via shuffles (wave-local, no LDS) ----
    unsigned ad[KKc], pw01[KKc], pw23[KKc];     // 27 persistent VGPRs
    #pragma unroll
    for (int k = 0; k < KKc; ++k) {
        int src  = (k < 8) ? ((k >> 1) * 16 + l15) : l15;
        int slot = (k < 8) ? (k & 1) : 2;
        ad[k]   = (unsigned)__shfl((int)my_ad[slot],  src, 64);
        pw01[k] = (unsigned)__shfl((int)my_w01[slot], src, 64);
        pw23[k] = (unsigned)__shfl((int)my_w23[slot], src, 64);
    }
    __syncthreads();                        // bar2: wkb visible

    f32x4 acc[2];
    acc[0] = (f32x4){0.f, 0.f, 0.f, 0.f};
    acc[1] = (f32x4){0.f, 0.f, 0.f, 0.f};

    // ---- software-pipelined barrier-free main loop ----
    uint4 R[2][8];
    int co0 = quad * 8, co1 = 32 + quad * 8;

    #define FETCH(kk, st)                                            \
        do {                                                         \
            unsigned ad_ = ad[kk];                                   \
            unsigned xc_ = ad_ >> 16;                                \
            unsigned at_ = (((ad_ & 255u) << 7) + xc_) << 6;         \
            unsigned ab_ = ((((ad_ >> 8) & 255u) << 7) + xc_) << 6;  \
            R[st][0] = *(const uint4*)(xtb + at_ + co0);             \
            R[st][1] = *(const uint4*)(xtb + at_ + 64 + co0);        \
            R[st][2] = *(const uint4*)(xtb + ab_ + co0);             \
            R[st][3] = *(const uint4*)(xtb + ab_ + 64 + co0);        \
            R[st][4] = *(const uint4*)(xtb + at_ + co1);             \
            R[st][5] = *(const uint4*)(xtb + at_ + 64 + co1);        \
            R[st][6] = *(const uint4*)(xtb + ab_ + co1);             \
            R[st][7] = *(const uint4*)(xtb + ab_ + 64 + co1);        \
        } while (0)

    FETCH(0, 0);
    #pragma unroll
    for (int k = 0; k < KKc; ++k) {
        if (k < KKc - 1) FETCH(k + 1, (k + 1) & 1);
        const uint4* C = R[k & 1];
        union { unsigned u; __half2 hv; } c01, c23;
        c01.u = pw01[k]; c23.u = pw23[k];
        float W0 = __low2float(c01.hv), W1 = __high2float(c01.hv);
        float W2 = __low2float(c23.hv), W3 = __high2float(c23.hv);
        #pragma unroll
        for (int kc = 0; kc < 2; ++kc) {
            const unsigned* t0 = (const unsigned*)&C[kc * 4 + 0];
            const unsigned* t1 = (const unsigned*)&C[kc * 4 + 1];
            const unsigned* b0 = (const unsigned*)&C[kc * 4 + 2];
            const unsigned* b1 = (const unsigned*)&C[kc * 4 + 3];
            union { bf16x8 v; unsigned u[4]; } bf;
            #pragma unroll
            for (int jd = 0; jd < 4; ++jd) {
                f32x2 t0p = {__uint_as_float(t0[jd] << 16),
                             __uint_as_float(t0[jd] & 0xFFFF0000u)};
                f32x2 t1p = {__uint_as_float(t1[jd] << 16),
                             __uint_as_float(t1[jd] & 0xFFFF0000u)};
                f32x2 b0p = {__uint_as_float(b0[jd] << 16),
                             __uint_as_float(b0[jd] & 0xFFFF0000u)};
                f32x2 b1p = {__uint_as_float(b1[jd] << 16),
                             __uint_as_float(b1[jd] & 0xFFFF0000u)};
                f32x2 vv = t0p * W0 + t1p * W1 + b0p * W2 + b1p * W3;
                unsigned pk;
                asm("v_cvt_pk_bf16_f32 %0, %1, %2"
                    : "=v"(pk) : "v"(vv.x), "v"(vv.y));
                bf.u[jd] = pk;
            }
            #pragma unroll
            for (int ot2 = 0; ot2 < 2; ++ot2) {
                bf16x8 af = s_w[((k * 2 + kc) * 2 + ot2) * 64 + lane];
                acc[ot2] = __builtin_amdgcn_mfma_f32_16x16x32_bf16(af, bf.v, acc[ot2], 0, 0, 0);
            }
        }
    }
    #undef FETCH

    #pragma unroll
    for (int ot2 = 0; ot2 < 2; ++ot2)
        #pragma unroll
        for (int r = 0; r < 4; ++r) {
            int o = ch * 32 + ot2 * 16 + quad * 4 + r;
            out[(((size_t)b * COUTc + o) * Hn + h) * Wn + p] = acc[ot2][r];
        }
}

// ---------------------------------------------------------------------------
extern "C" void kernel_launch(void* const* d_in, const int* in_sizes, int n_in,
                              void* d_out, int out_size, void* d_ws, size_t ws_size,
                              hipStream_t stream) {
    const float* x     = (const float*)d_in[0];
    const float* w_off = (const float*)d_in[1];
    const float* b_off = (const float*)d_in[2];
    const float* w_def = (const float*)d_in[3];
    float* out = (float*)d_out;

    char* ws = (char*)d_ws;
    unsigned short* xt = (unsigned short*)ws;                 // 8.39 MB
    ws += (size_t)Bn * HW * CINc * sizeof(unsigned short);
    unsigned short* wkb_sw = (unsigned short*)ws;             // 73728 B (2 halves)
    ws += 36864 * sizeof(unsigned short);
    unsigned short* wob_sw = (unsigned short*)ws;             // 36864 B

    prep_all<<<1024 + 216, 256, 0, stream>>>(x, xt, w_off, w_def, wkb_sw, wob_sw);
    fused_deform_v12<<<Bn * Hn * 2, 512, 0, stream>>>(xt, wob_sw, wkb_sw, b_off, out);
}

// Round 5
// 115.460 us; speedup vs baseline: 1.3369x; 1.3369x over previous
//
#include <hip/hip_runtime.h>
#include <hip/hip_fp16.h>

#define Bn   4
#define CINc 64
#define COUTc 64
#define Hn   128
#define Wn   128
#define HW   (Hn * Wn)
#define KKc  9
#define NOFF 18

typedef short bf16x8 __attribute__((ext_vector_type(8)));
typedef float f32x4  __attribute__((ext_vector_type(4)));
typedef float f32x2  __attribute__((ext_vector_type(2)));

__device__ inline unsigned short f2bf(float f) {   // RNE fp32 -> bf16
    unsigned int u = __float_as_uint(f);
    return (unsigned short)((u + 0x7fffu + ((u >> 16) & 1u)) >> 16);
}

// 16B global -> LDS DMA. lds base wave-uniform; HW writes lane's 16B at
// ldsbase + lane*16.
__device__ inline void dma16(const void* g, void* l) {
#if __has_builtin(__builtin_amdgcn_global_load_lds)
    __builtin_amdgcn_global_load_lds(
        (__attribute__((address_space(1))) void*)(g),
        (__attribute__((address_space(3))) void*)(l), 16, 0, 0);
#else
    *(uint4*)l = *(const uint4*)g;
#endif
}

// ---------------------------------------------------------------------------
// prep_all (v11 layout): blocks 0..1023 transpose x -> channel-last bf16 xt;
// blocks 1024..1239 build lane-order swizzled weight tables (wkb linear segs).
// ---------------------------------------------------------------------------
__global__ __launch_bounds__(256) void prep_all(
        const float* __restrict__ x, unsigned short* __restrict__ xt,
        const float* __restrict__ w_off, const float* __restrict__ w_def,
        unsigned short* __restrict__ wkb_sw, unsigned short* __restrict__ wob_sw) {
    int gb = blockIdx.x;
    int t  = threadIdx.x;
    if (gb < 1024) {
        __shared__ float s[64][65];
        int half = gb & 1;
        int h    = (gb >> 1) & 127;
        int b    = gb >> 8;
        int w0   = half * 64;
        int w = t & 63, cg = t >> 6;

        const float* xb = x + (size_t)b * CINc * HW + (size_t)h * Wn + w0 + w;
        #pragma unroll
        for (int i = 0; i < 16; ++i) {
            int c = cg * 16 + i;
            s[c][w] = xb[(size_t)c * HW];
        }
        __syncthreads();

        int cpair = t & 31, pxg = t >> 5;
        unsigned* xtp = (unsigned*)xt;
        #pragma unroll
        for (int i = 0; i < 8; ++i) {
            int px = pxg * 8 + i;
            float v0 = s[cpair * 2][px], v1 = s[cpair * 2 + 1][px];
            unsigned d = (unsigned)f2bf(v0) | ((unsigned)f2bf(v1) << 16);
            xtp[(((size_t)(b * Hn + h) * Wn) + w0 + px) * 32 + cpair] = d;
        }
        return;
    }
    int idx = (gb - 1024) * 256 + t;
    if (idx < 36864) {
        int j = idx & 7, l = (idx >> 3) & 63, s = idx >> 9;
        int k = s >> 3, kc = (s >> 2) & 1, ot = s & 3;
        int l15 = l & 15, quad = l >> 4;
        int o = ot * 16 + l15, c = kc * 32 + quad * 8 + j;
        wkb_sw[idx] = f2bf(w_def[((size_t)o * 64 + c) * 9 + k]);
    }
    int i2 = idx - 36864;
    if (i2 >= 0 && i2 < 18432) {
        int j = i2 & 7, l = (i2 >> 3) & 63, s = i2 >> 9;
        int tt = s >> 2, kc = (s >> 1) & 1, mt = s & 1;
        int l15 = l & 15, quad = l >> 4;
        int m = mt * 16 + l15, c = kc * 32 + quad * 8 + j;
        unsigned short v = 0;
        if (m < NOFF) v = f2bf(w_off[((size_t)m * 64 + c) * 9 + tt]);
        wob_sw[i2] = v;
    }
}

// ---------------------------------------------------------------------------
// Fused deformable conv v13 = v11 (512 blocks, full cout, measured 47.5us)
// with LDS shrunk 73.7KB -> 40KB by two-phase wkb staging:
//   s_w = 40 segs (40960 B). wob uses 36. wkb part A (taps 0..3, segs 0..31)
//   staged after bar1; part B (taps 4..8, segs 32..71 -> s_w[0..39]) staged
//   after bar3 (all part-A reads done), with tap-4's interp VALU covering the
//   DMA flight before bar4. Targets residency: 73.7KB*2+reserve > 160KB
//   (v11 measured 1.16 blocks/CU) -> 40KB*3 = 120KB fits comfortably.
// ---------------------------------------------------------------------------

// build one kc's bf16x8 MFMA B-operand from gathered rows + bilinear weights
#define BFBUILD(C, kc, BF, W0, W1, W2, W3)                                   \
    do {                                                                     \
        const unsigned* t0 = (const unsigned*)&(C)[(kc) * 4 + 0];            \
        const unsigned* t1 = (const unsigned*)&(C)[(kc) * 4 + 1];            \
        const unsigned* b0 = (const unsigned*)&(C)[(kc) * 4 + 2];            \
        const unsigned* b1 = (const unsigned*)&(C)[(kc) * 4 + 3];            \
        _Pragma("unroll")                                                    \
        for (int jd = 0; jd < 4; ++jd) {                                     \
            f32x2 t0p = {__uint_as_float(t0[jd] << 16),                      \
                         __uint_as_float(t0[jd] & 0xFFFF0000u)};             \
            f32x2 t1p = {__uint_as_float(t1[jd] << 16),                      \
                         __uint_as_float(t1[jd] & 0xFFFF0000u)};             \
            f32x2 b0p = {__uint_as_float(b0[jd] << 16),                      \
                         __uint_as_float(b0[jd] & 0xFFFF0000u)};             \
            f32x2 b1p = {__uint_as_float(b1[jd] << 16),                      \
                         __uint_as_float(b1[jd] & 0xFFFF0000u)};             \
            f32x2 vv = t0p * (W0) + t1p * (W1) + b0p * (W2) + b1p * (W3);    \
            unsigned pk;                                                     \
            asm("v_cvt_pk_bf16_f32 %0, %1, %2"                               \
                : "=v"(pk) : "v"(vv.x), "v"(vv.y));                          \
            (BF).u[jd] = pk;                                                 \
        }                                                                    \
    } while (0)

// full tap: unpack weights, build both kc operands, 8 MFMAs into acc[0..3]
#define TAP(k, SOFF)                                                         \
    do {                                                                     \
        const uint4* C = R[(k) & 1];                                         \
        union { unsigned u; __half2 hv; } c01, c23;                          \
        c01.u = pw01[(k)]; c23.u = pw23[(k)];                                \
        float W0 = __low2float(c01.hv), W1 = __high2float(c01.hv);           \
        float W2 = __low2float(c23.hv), W3 = __high2float(c23.hv);           \
        union { bf16x8 v; unsigned u[4]; } bfa, bfb;                         \
        BFBUILD(C, 0, bfa, W0, W1, W2, W3);                                  \
        BFBUILD(C, 1, bfb, W0, W1, W2, W3);                                  \
        _Pragma("unroll")                                                    \
        for (int ot = 0; ot < 4; ++ot) {                                     \
            bf16x8 af0 = s_w[(((k) * 2 + 0) * 4 + ot + (SOFF)) * 64 + lane]; \
            acc[ot] = __builtin_amdgcn_mfma_f32_16x16x32_bf16(               \
                af0, bfa.v, acc[ot], 0, 0, 0);                               \
            bf16x8 af1 = s_w[(((k) * 2 + 1) * 4 + ot + (SOFF)) * 64 + lane]; \
            acc[ot] = __builtin_amdgcn_mfma_f32_16x16x32_bf16(               \
                af1, bfb.v, acc[ot], 0, 0, 0);                               \
        }                                                                    \
    } while (0)

__global__ __launch_bounds__(512, 4) void fused_deform_v13(
        const unsigned short* __restrict__ xt,
        const unsigned short* __restrict__ wob_sw,
        const unsigned short* __restrict__ wkb_sw,
        const float* __restrict__ b_off, float* __restrict__ out) {
    __shared__ bf16x8 s_w[40 * 64];         // 40960 B (wob 36 / wkb-A 32 / wkb-B 40)

    int gid  = blockIdx.x;                  // 512
    int xcd  = gid & 7;
    int j    = gid >> 3;                    // 0..63
    int hh   = j & 15;
    int b    = j >> 4;
    int h    = xcd * 16 + hh;
    int tid  = threadIdx.x;
    int lane = tid & 63;
    int wave = __builtin_amdgcn_readfirstlane(tid >> 6);   // 0..7
    int l15  = lane & 15;
    int quad = lane >> 4;
    int p    = wave * 16 + l15;             // this lane's pixel col (0..127)

    // ---- stage wob -> s_w[0..36 segs) via DMA ----
    #pragma unroll
    for (int i = 0; i < 5; ++i) {
        int seg = i * 8 + wave;             // wave-uniform
        if (seg < 36) {
            int ebase = seg * 64;
            dma16((const uint4*)wob_sw + ebase + lane,
                  (char*)s_w + (size_t)ebase * 16);
        }
    }

    // ---- prefetch the 18 offset-tap fragments ----
    uint4 L[9][2];
    unsigned msk[9];
    const unsigned short* xtb = xt + (size_t)b * HW * 64;
    #pragma unroll
    for (int t9 = 0; t9 < 9; ++t9) {
        int ty = t9 / 3, tx = t9 % 3;
        int y  = h - 1 + ty;
        int xg = p - 1 + tx;
        bool v = (y >= 0) && (y < Hn) && (xg >= 0) && (xg < Wn);
        msk[t9] = v ? 0xFFFFFFFFu : 0u;
        int yc = min(max(y, 0), Hn - 1);
        int xc = min(max(xg, 0), Wn - 1);
        size_t base = ((size_t)yc * Wn + xc) * 64;
        L[t9][0] = *(const uint4*)(xtb + base + quad * 8);
        L[t9][1] = *(const uint4*)(xtb + base + 32 + quad * 8);
    }
    __syncthreads();                        // bar0: wob DMA + prefetch drained

    // ---- offset conv phase: 36 MFMA ----
    f32x4 oa0 = (f32x4){0.f, 0.f, 0.f, 0.f};
    f32x4 oa1 = (f32x4){0.f, 0.f, 0.f, 0.f};
    #pragma unroll
    for (int t9 = 0; t9 < 9; ++t9) {
        unsigned m = msk[t9];
        #pragma unroll
        for (int kc = 0; kc < 2; ++kc) {
            union { bf16x8 v; uint4 u; } bf;
            bf.u = L[t9][kc];
            bf.u.x &= m; bf.u.y &= m; bf.u.z &= m; bf.u.w &= m;
            bf16x8 a0 = s_w[((t9 * 2 + kc) * 2 + 0) * 64 + lane];
            bf16x8 a1 = s_w[((t9 * 2 + kc) * 2 + 1) * 64 + lane];
            oa0 = __builtin_amdgcn_mfma_f32_16x16x32_bf16(a0, bf.v, oa0, 0, 0, 0);
            oa1 = __builtin_amdgcn_mfma_f32_16x16x32_bf16(a1, bf.v, oa1, 0, 0, 0);
        }
    }

    // ---- phase-1 in registers; lane (l15,q) computes taps 2q,2q+1 (+8:q0)
    unsigned my_ad[3]  = {0, 0, 0};
    unsigned my_w01[3] = {0, 0, 0};
    unsigned my_w23[3] = {0, 0, 0};
    auto phase1 = [&](int k, float dy, float dx, int slot) {
        float py  = (float)(h - 1 + k / 3) + dy;
        float pxf = (float)(p - 1 + k % 3) + dx;
        float y0f = floorf(py), x0f = floorf(pxf);
        float fy = py - y0f, fx = pxf - x0f;
        int y0 = (int)y0f, x0 = (int)x0f;
        bool vy0 = (y0 >= 0) & (y0 < Hn);
        bool vy1 = (y0 + 1 >= 0) & (y0 + 1 < Hn);
        bool vx0 = (x0 >= 0) & (x0 < Wn);
        bool vx1 = (x0 + 1 >= 0) & (x0 + 1 < Wn);
        float wy0 = vy0 ? 1.f - fy : 0.f;
        float wy1 = vy1 ? fy : 0.f;
        float wx0 = vx0 ? 1.f - fx : 0.f;
        float wx1 = vx1 ? fx : 0.f;
        int xc = min(max(x0, 0), Wn - 2);               // pair base
        bool sel0 = (min(max(x0, 0), Wn - 1) != xc);
        bool sel1 = ((min(max(x0 + 1, 0), Wn - 1) - xc) == 1);
        float Wa = (sel0 ? 0.f : wx0) + (sel1 ? 0.f : wx1);
        float Wb = (sel0 ? wx0 : 0.f) + (sel1 ? wx1 : 0.f);
        int yc0 = min(max(y0, 0), Hn - 1), yc1 = min(max(y0 + 1, 0), Hn - 1);
        union { __half2 hv; unsigned u; } c01, c23;
        c01.hv = __floats2half2_rn(wy0 * Wa, wy0 * Wb);
        c23.hv = __floats2half2_rn(wy1 * Wa, wy1 * Wb);
        my_ad[slot]  = (unsigned)yc0 | ((unsigned)yc1 << 8) | ((unsigned)xc << 16);
        my_w01[slot] = c01.u;
        my_w23[slot] = c23.u;
    };
    int kb = quad * 2;
    phase1(kb,     oa0[0] + b_off[4 * quad],     oa0[1] + b_off[4 * quad + 1], 0);
    phase1(kb + 1, oa0[2] + b_off[4 * quad + 2], oa0[3] + b_off[4 * quad + 3], 1);
    if (quad == 0)
        phase1(8, oa1[0] + b_off[16], oa1[1] + b_off[17], 2);
    __syncthreads();                        // bar1: all wob ds_reads done

    // ---- stage wkb part A (taps 0..3 = segs 0..31) via DMA ----
    #pragma unroll
    for (int i = 0; i < 4; ++i) {
        int seg = i * 8 + wave;             // 32 segs over 8 waves
        dma16((const uint4*)wkb_sw + (size_t)seg * 64 + lane,
              (char*)s_w + (size_t)seg * 1024);
    }

    // ---- redistribute phase-1 via shuffles (wave-local, no LDS) ----
    unsigned at[KKc], ab[KKc];
    unsigned pw01[KKc], pw23[KKc];
    #pragma unroll
    for (int k = 0; k < KKc; ++k) {
        int src  = (k < 8) ? ((k >> 1) * 16 + l15) : l15;
        int slot = (k < 8) ? (k & 1) : 2;
        unsigned ad  = (unsigned)__shfl((int)my_ad[slot],  src, 64);
        pw01[k] = (unsigned)__shfl((int)my_w01[slot], src, 64);
        pw23[k] = (unsigned)__shfl((int)my_w23[slot], src, 64);
        int xc = (int)(ad >> 16);
        at[k] = (unsigned)(((ad & 255u) * Wn + xc) * 64);
        ab[k] = (unsigned)((((ad >> 8) & 255u) * Wn + xc) * 64);
    }
    __syncthreads();                        // bar2: wkb-A visible

    f32x4 acc[4];
    #pragma unroll
    for (int ot = 0; ot < 4; ++ot) acc[ot] = (f32x4){0.f, 0.f, 0.f, 0.f};

    uint4 R[2][8];
    int co0 = quad * 8, co1 = 32 + quad * 8;

    #define FETCH(kk, st)                                            \
        do {                                                         \
            R[st][0] = *(const uint4*)(xtb + at[kk] + co0);          \
            R[st][1] = *(const uint4*)(xtb + at[kk] + 64 + co0);     \
            R[st][2] = *(const uint4*)(xtb + ab[kk] + co0);          \
            R[st][3] = *(const uint4*)(xtb + ab[kk] + 64 + co0);     \
            R[st][4] = *(const uint4*)(xtb + at[kk] + co1);          \
            R[st][5] = *(const uint4*)(xtb + at[kk] + 64 + co1);     \
            R[st][6] = *(const uint4*)(xtb + ab[kk] + co1);          \
            R[st][7] = *(const uint4*)(xtb + ab[kk] + 64 + co1);     \
        } while (0)

    // ---- main loop, part 1: taps 0..3 from wkb-A ----
    FETCH(0, 0);
    FETCH(1, 1); TAP(0, 0);
    FETCH(2, 0); TAP(1, 0);
    FETCH(3, 1); TAP(2, 0);
    FETCH(4, 0); TAP(3, 0);
    __syncthreads();                        // bar3: all wkb-A reads done

    // ---- stage wkb part B (taps 4..8 = segs 32..71 -> s_w[0..39]) ----
    #pragma unroll
    for (int i = 0; i < 5; ++i) {
        int seg = i * 8 + wave;             // 40 segs over 8 waves
        dma16((const uint4*)wkb_sw + (size_t)(32 + seg) * 64 + lane,
              (char*)s_w + (size_t)seg * 1024);
    }

    // ---- tap-4 bridge: interp VALU covers the wkb-B DMA flight ----
    union { bf16x8 v; unsigned u[4]; } bf40, bf41;
    {
        const uint4* C = R[0];
        union { unsigned u; __half2 hv; } c01, c23;
        c01.u = pw01[4]; c23.u = pw23[4];
        float W0 = __low2float(c01.hv), W1 = __high2float(c01.hv);
        float W2 = __low2float(c23.hv), W3 = __high2float(c23.hv);
        BFBUILD(C, 0, bf40, W0, W1, W2, W3);
        BFBUILD(C, 1, bf41, W0, W1, W2, W3);
    }
    FETCH(5, 1);
    __syncthreads();                        // bar4: wkb-B visible

    #pragma unroll
    for (int ot = 0; ot < 4; ++ot) {        // tap 4 MFMAs: segs 32..39 -> 0..7
        bf16x8 af0 = s_w[(0 + ot) * 64 + lane];
        acc[ot] = __builtin_amdgcn_mfma_f32_16x16x32_bf16(af0, bf40.v, acc[ot], 0, 0, 0);
        bf16x8 af1 = s_w[(4 + ot) * 64 + lane];
        acc[ot] = __builtin_amdgcn_mfma_f32_16x16x32_bf16(af1, bf41.v, acc[ot], 0, 0, 0);
    }

    // ---- main loop, part 2: taps 5..8 from wkb-B (seg offset -32) ----
    FETCH(6, 0); TAP(5, -32);
    FETCH(7, 1); TAP(6, -32);
    FETCH(8, 0); TAP(7, -32);
    TAP(8, -32);
    #undef FETCH

    #pragma unroll
    for (int ot = 0; ot < 4; ++ot)
        #pragma unroll
        for (int r = 0; r < 4; ++r) {
            int o = ot * 16 + quad * 4 + r;
            out[(((size_t)b * COUTc + o) * Hn + h) * Wn + p] = acc[ot][r];
        }
}

// ---------------------------------------------------------------------------
extern "C" void kernel_launch(void* const* d_in, const int* in_sizes, int n_in,
                              void* d_out, int out_size, void* d_ws, size_t ws_size,
                              hipStream_t stream) {
    const float* x     = (const float*)d_in[0];
    const float* w_off = (const float*)d_in[1];
    const float* b_off = (const float*)d_in[2];
    const float* w_def = (const float*)d_in[3];
    float* out = (float*)d_out;

    char* ws = (char*)d_ws;
    unsigned short* xt = (unsigned short*)ws;                 // 8.39 MB
    ws += (size_t)Bn * HW * CINc * sizeof(unsigned short);
    unsigned short* wkb_sw = (unsigned short*)ws;             // 73728 B
    ws += 36864 * sizeof(unsigned short);
    unsigned short* wob_sw = (unsigned short*)ws;             // 36864 B

    prep_all<<<1024 + 216, 256, 0, stream>>>(x, xt, w_off, w_def, wkb_sw, wob_sw);
    fused_deform_v13<<<Bn * Hn, 512, 0, stream>>>(xt, wob_sw, wkb_sw, b_off, out);
}